// Round 3
// baseline (395.220 us; speedup 1.0000x reference)
//
#include <hip/hip_runtime.h>

#define NT 32768
#define DM 1024
#define NTOT (NT + 128)          // 32896 = 257 * 128 ; 128-row gap separates experts
#define NKT (DM / 64)            // 16 K-steps of BK=64

typedef __bf16 bf16x8 __attribute__((ext_vector_type(8)));
typedef __bf16 bf16x4 __attribute__((ext_vector_type(4)));
typedef float f32x4 __attribute__((ext_vector_type(4)));

// async global->LDS, 16B per lane; LDS dest is wave-uniform base + lane*16
#define GLD16(g, l)                                                            \
  __builtin_amdgcn_global_load_lds(                                            \
      (const __attribute__((address_space(1))) void*)(g),                      \
      (__attribute__((address_space(3))) void*)(l), 16, 0, 0)

__device__ __forceinline__ unsigned short f2bf(float f) {
  unsigned u = __float_as_uint(f);
  u += 0x7fffu + ((u >> 16) & 1u);   // RNE
  return (unsigned short)(u >> 16);
}

// ------- weight convert+transpose: Wt[e][n][k] = bf16(W_e[k][n]); both experts via z -------
__global__ void wt_k(const float* __restrict__ W1, const float* __restrict__ W2,
                     unsigned short* __restrict__ Wt) {
  const float* __restrict__ W = blockIdx.z ? W2 : W1;
  unsigned short* __restrict__ dst = Wt + (size_t)blockIdx.z * DM * DM;
  __shared__ float tile[32][33];
  int tx = threadIdx.x, ty = threadIdx.y;           // 32 x 8
  int n0 = blockIdx.x * 32, k0 = blockIdx.y * 32;
#pragma unroll
  for (int i = 0; i < 32; i += 8)
    tile[ty + i][tx] = W[(size_t)(k0 + ty + i) * DM + n0 + tx];
  __syncthreads();
#pragma unroll
  for (int i = 0; i < 32; i += 8)
    dst[(size_t)(n0 + ty + i) * DM + k0 + tx] = f2bf(tile[tx][ty + i]);
}

// ------- routing: ONE workgroup, prefix-scan, ZERO global atomics -------
// (replaces 512-block version whose 1024 serialized same-address device-scope
//  atomics are the suspected ~100us hidden residue)
// thread t owns tokens [t*32, t*32+32); expert0 slots ascend from 0,
// expert1 slots descend from NTOT-1; gap [n0, n0+128) never written.
__global__ __launch_bounds__(1024) void route_k(const int* __restrict__ route,
                                                int* __restrict__ idx,
                                                int* __restrict__ counters) {
  __shared__ int wsum[16];
  const int t = threadIdx.x;
  const int lane = t & 63, wv = t >> 6;
  const int base = t * 32;
  const int4* rp = (const int4*)(route + base);
  unsigned mask = 0;
#pragma unroll
  for (int v = 0; v < 8; ++v) {
    int4 q = rp[v];
    mask |= (unsigned)(q.x == 0) << (v * 4 + 0);
    mask |= (unsigned)(q.y == 0) << (v * 4 + 1);
    mask |= (unsigned)(q.z == 0) << (v * 4 + 2);
    mask |= (unsigned)(q.w == 0) << (v * 4 + 3);
  }
  const int c0 = __popc(mask);
  int s = c0;                                   // within-wave inclusive scan
#pragma unroll
  for (int d = 1; d < 64; d <<= 1) {
    int v = __shfl_up(s, (unsigned)d, 64);
    if (lane >= d) s += v;
  }
  if (lane == 63) wsum[wv] = s;
  __syncthreads();
  int waveBase = 0, total0 = 0;                 // 16 broadcast LDS reads, cheap
#pragma unroll
  for (int w = 0; w < 16; ++w) {
    int v = wsum[w];
    if (w < wv) waveBase += v;
    total0 += v;
  }
  const int ex0 = waveBase + s - c0;            // exclusive prefix of expert0 count
  int slot0 = ex0;
  int slot1 = NTOT - 1 - (base - ex0);
#pragma unroll
  for (int i = 0; i < 32; ++i) {
    int token = base + i;
    if ((mask >> i) & 1) idx[slot0++] = token;
    else                 idx[slot1--] = token;
  }
  if (t == 0) { counters[0] = total0; counters[1] = NT - total0; }
}

// ------- fused gather+convert grouped GEMM: 128x128 tile, BK=64 -------
// A: gathered from x (fp32) via idx -> regs, cvt_pk'd to bf16, ds_write'd
//    swizzled into single-buffer As (16 KiB). B: global_load_lds into
//    double-buffered Bs (32 KiB). 48 KiB total -> 3 blk/CU.
// Sync scheme (T4 counted-wait in disguise):
//   WRITEA (auto vmcnt(4) for a[]; loads a full iter old)
//   bar1 = __syncthreads  (its vmcnt(0) drains only STAGEB(kt), issued last
//                          iter -> free; makes As(kt) visible)
//   LOADA(kt+1); STAGEB(kt+1 -> buf^1)   // 12 loads issued, stay in flight
//   MFMA(kt)
//   bar2 = lgkmcnt(0) + raw s_barrier    // NO vmcnt -> loads cross barrier
__global__ __launch_bounds__(256, 3) void gemm_k(
    const float* __restrict__ x,              // [NT][DM] fp32
    const unsigned short* __restrict__ Wt,    // [2][DM][DM] bf16, Wt[n][k]
    const float* __restrict__ b1, const float* __restrict__ b2,
    const int* __restrict__ idx, const int* __restrict__ counters,
    float* __restrict__ out) {
  __shared__ unsigned short As[128 * 64];     // swizzled [row][k-chunk], single buf
  __shared__ unsigned short Bs[2][128 * 64];  // double buf

  const int t = threadIdx.x;
  const int lane = t & 63, wave = t >> 6;

  // XCD-aware bijective swizzle: 2056 blocks = 8 XCDs x 257; the 8 col-tiles of
  // each 128-row A-panel get consecutive logical ids on the SAME XCD.
  const int lin = blockIdx.y * 8 + blockIdx.x;       // dispatch order, x fastest
  const int L = (lin & 7) * 257 + (lin >> 3);        // bijective since 2056 % 8 == 0
  const int row0 = (L >> 3) * 128;
  const int col0 = (L & 7) * 128;

  const int n0 = counters[0];
  const int expert = (row0 < n0) ? 0 : 1;   // 128-gap => tiles never mix experts
  const unsigned short* Wte = Wt + (size_t)expert * DM * DM;
  const float* bias = expert ? b2 : b1;

  const int wr = (wave >> 1) * 64;
  const int wc = (wave & 1) * 64;
  const int lr = lane & 15;

  // per-thread A gather setup: 8 rows (p*16 + t>>4), 16B-fp32 chunk (t&15)
  const int rsub = t >> 4;
  const int c16 = t & 15;
  const float* rowp[8];
#pragma unroll
  for (int p = 0; p < 8; ++p) {
    int gr = row0 + p * 16 + rsub;
    int tok = idx[gr];
    if (gr >= n0 && gr < n0 + 128) tok = 0;   // gap rows: valid dummy, discarded later
    rowp[p] = x + (size_t)tok * DM;
  }

  float4 a[8];
  f32x4 acc[4][4] = {};

#define LOADA(k0)                                                              \
  _Pragma("unroll") for (int p = 0; p < 8; ++p)                                \
      a[p] = *(const float4*)(rowp[p] + (k0) + c16 * 4);

// write a[] as bf16 into swizzled As: chunk c of row r lives at chunk r*8+(c^(r&7))
// native casts -> compiler emits v_cvt_pk_bf16_f32 (RNE, same as f2bf)
#define WRITEA()                                                               \
  _Pragma("unroll") for (int p = 0; p < 8; ++p) {                              \
    int r = p * 16 + rsub;                                                     \
    int off = (r * 8 + ((c16 >> 1) ^ (r & 7))) * 16 + (c16 & 1) * 8;           \
    bf16x4 pk;                                                                 \
    pk[0] = (__bf16)a[p].x; pk[1] = (__bf16)a[p].y;                            \
    pk[2] = (__bf16)a[p].z; pk[3] = (__bf16)a[p].w;                            \
    *(bf16x4*)((char*)&As[0] + off) = pk;                                      \
  }

#define STAGEB(k0, bufw)                                                       \
  _Pragma("unroll") for (int p = 0; p < 4; ++p) {                              \
    int q = p * 256 + t;                                                       \
    int r = q >> 3;                                                            \
    int c = ((q & 7) ^ (r & 7)) * 8;                                           \
    GLD16(Wte + (size_t)(col0 + r) * DM + (k0) + c, &Bs[bufw][q * 8]);         \
  }

  // prologue: A(0) into regs, B(0) into Bs[0]
  LOADA(0);
  STAGEB(0, 0);

#pragma unroll 2
  for (int kt = 0; kt < NKT; ++kt) {
    const int buf = kt & 1;
    WRITEA();                  // consumes a[] = A(kt); auto-wait vmcnt(4)
    __syncthreads();           // As(kt) visible; drains STAGEB(kt) (iter-old, free)
    if (kt < NKT - 1) {
      LOADA((kt + 1) * 64);            // 8 loads -> regs, in flight across bar2
      STAGEB((kt + 1) * 64, buf ^ 1);  // 4 loads -> other LDS buf, ditto
    }
#pragma unroll
    for (int s = 0; s < 2; ++s) {
      const int cb = s * 4 + (lane >> 4);   // wanted 16B chunk within the row
      bf16x8 af[4], bfr[4];
#pragma unroll
      for (int i = 0; i < 4; ++i) {
        int r = wr + i * 16 + lr;
        af[i] = *(const bf16x8*)&As[(r * 8 + (cb ^ (r & 7))) * 8];
      }
#pragma unroll
      for (int j = 0; j < 4; ++j) {
        int r = wc + j * 16 + lr;
        bfr[j] = *(const bf16x8*)&Bs[buf][(r * 8 + (cb ^ (r & 7))) * 8];
      }
#pragma unroll
      for (int i = 0; i < 4; ++i)
#pragma unroll
        for (int j = 0; j < 4; ++j)
          acc[i][j] = __builtin_amdgcn_mfma_f32_16x16x32_bf16(af[i], bfr[j], acc[i][j], 0, 0, 0);
    }
    // bar2: lgkm-only raw barrier -- all waves' ds_reads of As/Bs[buf] done,
    // but the 12 just-issued loads stay in flight (no vmcnt). sched_barrier
    // pins ordering around the inline asm (rule #18).
    asm volatile("s_waitcnt lgkmcnt(0)" ::: "memory");
    __builtin_amdgcn_sched_barrier(0);
    __builtin_amdgcn_s_barrier();
    __builtin_amdgcn_sched_barrier(0);
  }

  // epilogue: scatter rows to original token positions, add bias (fp32).
#pragma unroll
  for (int i = 0; i < 4; ++i) {
#pragma unroll
    for (int reg = 0; reg < 4; ++reg) {
      int gr = row0 + wr + i * 16 + (lane >> 4) * 4 + reg;
      if (gr < n0 || gr >= n0 + 128) {
        int dest = idx[gr];
#pragma unroll
        for (int j = 0; j < 4; ++j) {
          int gc = col0 + wc + j * 16 + (lane & 15);
          out[(size_t)dest * DM + gc] = acc[i][j][reg] + bias[gc];
        }
      }
    }
  }
#undef LOADA
#undef WRITEA
#undef STAGEB
}

extern "C" void kernel_launch(void* const* d_in, const int* in_sizes, int n_in,
                              void* d_out, int out_size, void* d_ws, size_t ws_size,
                              hipStream_t stream) {
  const float* x   = (const float*)d_in[0];
  const float* W1  = (const float*)d_in[1];
  const float* b1  = (const float*)d_in[2];
  const float* W2  = (const float*)d_in[3];
  const float* b2  = (const float*)d_in[4];
  const int*   route = (const int*)d_in[5];
  float* out = (float*)d_out;

  char* ws = (char*)d_ws;
  unsigned short* Wt = (unsigned short*)ws;            // 2*DM*DM bf16 = 4 MB
  size_t off = (size_t)2 * DM * DM * 2;
  int* idx = (int*)(ws + off);                         // NTOT ints
  int* counters = idx + NTOT;                          // 2 ints

  route_k<<<1, 1024, 0, stream>>>(route, idx, counters);
  wt_k<<<dim3(DM / 32, DM / 32, 2), dim3(32, 8), 0, stream>>>(W1, W2, Wt);
  gemm_k<<<dim3(8, NTOT / 128), 256, 0, stream>>>(x, Wt, b1, b2, idx, counters, out);
}

// Round 4
// 375.839 us; speedup vs baseline: 1.0516x; 1.0516x over previous
//
#include <hip/hip_runtime.h>

#define NT 32768
#define DM 1024
#define NTOT (NT + 128)          // 32896 = 257 * 128 ; 128-row gap separates experts
#define NKT (DM / 64)            // 16 K-steps of BK=64

typedef __bf16 bf16x8 __attribute__((ext_vector_type(8)));
typedef __bf16 bf16x4 __attribute__((ext_vector_type(4)));
typedef float f32x4 __attribute__((ext_vector_type(4)));

// async global->LDS, 16B per lane; LDS dest is wave-uniform base + lane*16
#define GLD16(g, l)                                                            \
  __builtin_amdgcn_global_load_lds(                                            \
      (const __attribute__((address_space(1))) void*)(g),                      \
      (__attribute__((address_space(3))) void*)(l), 16, 0, 0)

__device__ __forceinline__ unsigned short f2bf(float f) {
  unsigned u = __float_as_uint(f);
  u += 0x7fffu + ((u >> 16) & 1u);   // RNE
  return (unsigned short)(u >> 16);
}

// ------- weight convert+transpose: Wt[e][n][k] = bf16(W_e[k][n]); both experts via z -------
__global__ void wt_k(const float* __restrict__ W1, const float* __restrict__ W2,
                     unsigned short* __restrict__ Wt) {
  const float* __restrict__ W = blockIdx.z ? W2 : W1;
  unsigned short* __restrict__ dst = Wt + (size_t)blockIdx.z * DM * DM;
  __shared__ float tile[32][33];
  int tx = threadIdx.x, ty = threadIdx.y;           // 32 x 8
  int n0 = blockIdx.x * 32, k0 = blockIdx.y * 32;
#pragma unroll
  for (int i = 0; i < 32; i += 8)
    tile[ty + i][tx] = W[(size_t)(k0 + ty + i) * DM + n0 + tx];
  __syncthreads();
#pragma unroll
  for (int i = 0; i < 32; i += 8)
    dst[(size_t)(n0 + ty + i) * DM + k0 + tx] = f2bf(tile[tx][ty + i]);
}

// ------- routing: ONE workgroup, prefix-scan, ZERO global atomics -------
__global__ __launch_bounds__(1024) void route_k(const int* __restrict__ route,
                                                int* __restrict__ idx,
                                                int* __restrict__ counters) {
  __shared__ int wsum[16];
  const int t = threadIdx.x;
  const int lane = t & 63, wv = t >> 6;
  const int base = t * 32;
  const int4* rp = (const int4*)(route + base);
  unsigned mask = 0;
#pragma unroll
  for (int v = 0; v < 8; ++v) {
    int4 q = rp[v];
    mask |= (unsigned)(q.x == 0) << (v * 4 + 0);
    mask |= (unsigned)(q.y == 0) << (v * 4 + 1);
    mask |= (unsigned)(q.z == 0) << (v * 4 + 2);
    mask |= (unsigned)(q.w == 0) << (v * 4 + 3);
  }
  const int c0 = __popc(mask);
  int s = c0;                                   // within-wave inclusive scan
#pragma unroll
  for (int d = 1; d < 64; d <<= 1) {
    int v = __shfl_up(s, (unsigned)d, 64);
    if (lane >= d) s += v;
  }
  if (lane == 63) wsum[wv] = s;
  __syncthreads();
  int waveBase = 0, total0 = 0;
#pragma unroll
  for (int w = 0; w < 16; ++w) {
    int v = wsum[w];
    if (w < wv) waveBase += v;
    total0 += v;
  }
  const int ex0 = waveBase + s - c0;            // exclusive prefix of expert0 count
  int slot0 = ex0;
  int slot1 = NTOT - 1 - (base - ex0);
#pragma unroll
  for (int i = 0; i < 32; ++i) {
    int token = base + i;
    if ((mask >> i) & 1) idx[slot0++] = token;
    else                 idx[slot1--] = token;
  }
  if (t == 0) { counters[0] = total0; counters[1] = NT - total0; }
}

// ------- fused gather+convert grouped GEMM: 128x128 tile, BK=64 -------
// T3/T4 single-barrier counted-vmcnt 2-phase (m201/m230 pattern):
//   As, Bs both double-buffered (64 KiB -> 2 blk/CU); A gathered fp32 -> two
//   register sets a[2][8] (the reg-side double buffer), cvt'd to bf16,
//   ds_write'd swizzled. Per K-step t (buf = t&1, fully unrolled so all
//   indices are static):
//     (a) STAGEB(t+1 -> Bs[buf^1])        4 GLD16, oldest in flight
//     (b) LOADA (t+2 -> a[buf])           8 loads, newest in flight
//     (c) ds_read As[buf],Bs[buf] + 32 MFMA
//     (d) WRITEA a[buf^1]=A(t+1) -> As[buf^1]   (compiler auto-waits its loads,
//         which are ~2 iterations old)
//     (e) s_waitcnt vmcnt(8) lgkmcnt(0) + s_barrier : confirms STAGEB(t+1)
//         landed and ds ops visible; the 8 newest loads (LOADA t+2) STAY IN
//         FLIGHT across the barrier. vmcnt(0) only at t=NKT-2 (tail).
// Every vmem load gets >= 1 full iteration of latency coverage.
__global__ __launch_bounds__(256, 2) void gemm_k(
    const float* __restrict__ x,              // [NT][DM] fp32
    const unsigned short* __restrict__ Wt,    // [2][DM][DM] bf16, Wt[n][k]
    const float* __restrict__ b1, const float* __restrict__ b2,
    const int* __restrict__ idx, const int* __restrict__ counters,
    float* __restrict__ out) {
  __shared__ unsigned short As[2][128 * 64];  // swizzled [row][k-chunk]
  __shared__ unsigned short Bs[2][128 * 64];

  const int t = threadIdx.x;
  const int lane = t & 63, wave = t >> 6;

  // XCD-aware bijective swizzle: 2056 blocks = 8 XCDs x 257; the 8 col-tiles of
  // each 128-row A-panel get consecutive logical ids on the SAME XCD.
  const int lin = blockIdx.y * 8 + blockIdx.x;       // dispatch order, x fastest
  const int L = (lin & 7) * 257 + (lin >> 3);        // bijective since 2056 % 8 == 0
  const int row0 = (L >> 3) * 128;
  const int col0 = (L & 7) * 128;

  const int n0 = counters[0];
  const int expert = (row0 < n0) ? 0 : 1;   // 128-gap => tiles never mix experts
  const unsigned short* Wte = Wt + (size_t)expert * DM * DM;
  const float* bias = expert ? b2 : b1;

  const int wr = (wave >> 1) * 64;
  const int wc = (wave & 1) * 64;
  const int lr = lane & 15;

  // per-thread A gather setup: 8 rows (p*16 + t>>4), 16B-fp32 chunk (t&15)
  const int rsub = t >> 4;
  const int c16 = t & 15;
  const float* rowp[8];
#pragma unroll
  for (int p = 0; p < 8; ++p) {
    int gr = row0 + p * 16 + rsub;
    int tok = idx[gr];
    if (gr >= n0 && gr < n0 + 128) tok = 0;   // gap rows: valid dummy, discarded later
    rowp[p] = x + (size_t)tok * DM;
  }

  float4 a[2][8];                 // two A register sets (the reg-side dbuf)
  f32x4 acc[4][4] = {};

#define LOADA(k0, s)                                                           \
  _Pragma("unroll") for (int p = 0; p < 8; ++p)                                \
      a[s][p] = *(const float4*)(rowp[p] + (k0) + c16 * 4);

// write a[s] as bf16 into swizzled As[bufw]: chunk c of row r at chunk r*8+(c^(r&7))
#define WRITEA(s, bufw)                                                        \
  _Pragma("unroll") for (int p = 0; p < 8; ++p) {                              \
    int r = p * 16 + rsub;                                                     \
    int off = (r * 8 + ((c16 >> 1) ^ (r & 7))) * 16 + (c16 & 1) * 8;           \
    bf16x4 pk;                                                                 \
    pk[0] = (__bf16)a[s][p].x; pk[1] = (__bf16)a[s][p].y;                      \
    pk[2] = (__bf16)a[s][p].z; pk[3] = (__bf16)a[s][p].w;                      \
    *(bf16x4*)((char*)&As[bufw][0] + off) = pk;                                \
  }

#define STAGEB(k0, bufw)                                                       \
  _Pragma("unroll") for (int p = 0; p < 4; ++p) {                              \
    int q = p * 256 + t;                                                       \
    int r = q >> 3;                                                            \
    int c = ((q & 7) ^ (r & 7)) * 8;                                           \
    GLD16(Wte + (size_t)(col0 + r) * DM + (k0) + c, &Bs[bufw][q * 8]);         \
  }

  // prologue: A(0)->a[0]->As[0]; B(0)->Bs[0]; A(1)->a[1] (stays in flight)
  LOADA(0, 0);
  STAGEB(0, 0);
  WRITEA(0, 0);                  // compiler auto-waits a[0]'s 8 loads
  LOADA(64, 1);
  asm volatile("s_waitcnt vmcnt(8) lgkmcnt(0)" ::: "memory");  // STAGEB(0) landed
  __builtin_amdgcn_sched_barrier(0);
  __builtin_amdgcn_s_barrier();
  __builtin_amdgcn_sched_barrier(0);

#pragma unroll
  for (int kt = 0; kt < NKT; ++kt) {
    const int buf = kt & 1;
    if (kt < NKT - 1) STAGEB((kt + 1) * 64, buf ^ 1);   // 4 GLD16 -> Bs[buf^1]
    if (kt < NKT - 2) LOADA((kt + 2) * 64, buf);        // 8 loads -> a[buf]
#pragma unroll
    for (int s = 0; s < 2; ++s) {
      const int cb = s * 4 + (lane >> 4);   // wanted 16B chunk within the row
      bf16x8 af[4], bfr[4];
#pragma unroll
      for (int i = 0; i < 4; ++i) {
        int r = wr + i * 16 + lr;
        af[i] = *(const bf16x8*)&As[buf][(r * 8 + (cb ^ (r & 7))) * 8];
      }
#pragma unroll
      for (int j = 0; j < 4; ++j) {
        int r = wc + j * 16 + lr;
        bfr[j] = *(const bf16x8*)&Bs[buf][(r * 8 + (cb ^ (r & 7))) * 8];
      }
#pragma unroll
      for (int i = 0; i < 4; ++i)
#pragma unroll
        for (int j = 0; j < 4; ++j)
          acc[i][j] = __builtin_amdgcn_mfma_f32_16x16x32_bf16(af[i], bfr[j], acc[i][j], 0, 0, 0);
    }
    if (kt < NKT - 1) {
      WRITEA(buf ^ 1, buf ^ 1);  // A(kt+1) -> As[buf^1]; its loads are ~2 iters old
      if (kt <= NKT - 3)
        asm volatile("s_waitcnt vmcnt(8) lgkmcnt(0)" ::: "memory");  // keep 8 newest flying
      else
        asm volatile("s_waitcnt vmcnt(0) lgkmcnt(0)" ::: "memory");  // tail drain, once
      __builtin_amdgcn_sched_barrier(0);
      __builtin_amdgcn_s_barrier();
      __builtin_amdgcn_sched_barrier(0);
    }
  }

  // epilogue: scatter rows to original token positions, add bias (fp32).
#pragma unroll
  for (int i = 0; i < 4; ++i) {
#pragma unroll
    for (int reg = 0; reg < 4; ++reg) {
      int gr = row0 + wr + i * 16 + (lane >> 4) * 4 + reg;
      if (gr < n0 || gr >= n0 + 128) {
        int dest = idx[gr];
#pragma unroll
        for (int j = 0; j < 4; ++j) {
          int gc = col0 + wc + j * 16 + (lane & 15);
          out[(size_t)dest * DM + gc] = acc[i][j][reg] + bias[gc];
        }
      }
    }
  }
#undef LOADA
#undef WRITEA
#undef STAGEB
}

extern "C" void kernel_launch(void* const* d_in, const int* in_sizes, int n_in,
                              void* d_out, int out_size, void* d_ws, size_t ws_size,
                              hipStream_t stream) {
  const float* x   = (const float*)d_in[0];
  const float* W1  = (const float*)d_in[1];
  const float* b1  = (const float*)d_in[2];
  const float* W2  = (const float*)d_in[3];
  const float* b2  = (const float*)d_in[4];
  const int*   route = (const int*)d_in[5];
  float* out = (float*)d_out;

  char* ws = (char*)d_ws;
  unsigned short* Wt = (unsigned short*)ws;            // 2*DM*DM bf16 = 4 MB
  size_t off = (size_t)2 * DM * DM * 2;
  int* idx = (int*)(ws + off);                         // NTOT ints
  int* counters = idx + NTOT;                          // 2 ints

  route_k<<<1, 1024, 0, stream>>>(route, idx, counters);
  wt_k<<<dim3(DM / 32, DM / 32, 2), dim3(32, 8), 0, stream>>>(W1, W2, Wt);
  gemm_k<<<dim3(8, NTOT / 128), 256, 0, stream>>>(x, Wt, b1, b2, idx, counters, out);
}

// Round 5
// 350.843 us; speedup vs baseline: 1.1265x; 1.0712x over previous
//
#include <hip/hip_runtime.h>

#define NT 32768
#define DM 1024
#define NTOT (NT + 128)          // 32896 = 257 * 128 ; 128-row gap separates experts

typedef __bf16 bf16x8 __attribute__((ext_vector_type(8)));
typedef float f32x4 __attribute__((ext_vector_type(4)));

// async global->LDS, 16B per lane; LDS dest is wave-uniform base + lane*16
#define GLD16(g, l)                                                            \
  __builtin_amdgcn_global_load_lds(                                            \
      (const __attribute__((address_space(1))) void*)(g),                      \
      (__attribute__((address_space(3))) void*)(l), 16, 0, 0)

__device__ __forceinline__ unsigned short f2bf(float f) {
  unsigned u = __float_as_uint(f);
  u += 0x7fffu + ((u >> 16) & 1u);   // RNE
  return (unsigned short)(u >> 16);
}

// ------- weight convert+transpose: Wt[e][n][k] = bf16(W_e[k][n]); both experts via z -------
__global__ void wt_k(const float* __restrict__ W1, const float* __restrict__ W2,
                     unsigned short* __restrict__ Wt) {
  const float* __restrict__ W = blockIdx.z ? W2 : W1;
  unsigned short* __restrict__ dst = Wt + (size_t)blockIdx.z * DM * DM;
  __shared__ float tile[32][33];
  int tx = threadIdx.x, ty = threadIdx.y;           // 32 x 8
  int n0 = blockIdx.x * 32, k0 = blockIdx.y * 32;
#pragma unroll
  for (int i = 0; i < 32; i += 8)
    tile[ty + i][tx] = W[(size_t)(k0 + ty + i) * DM + n0 + tx];
  __syncthreads();
#pragma unroll
  for (int i = 0; i < 32; i += 8)
    dst[(size_t)(n0 + ty + i) * DM + k0 + tx] = f2bf(tile[tx][ty + i]);
}

// ------- routing: ONE workgroup, prefix-scan, ZERO global atomics -------
// thread t owns tokens [t*32, t*32+32); expert0 slots ascend from 0,
// expert1 slots descend from NTOT-1; gap [n0, n0+128) never written.
__global__ __launch_bounds__(1024) void route_k(const int* __restrict__ route,
                                                int* __restrict__ idx,
                                                int* __restrict__ counters) {
  __shared__ int wsum[16];
  const int t = threadIdx.x;
  const int lane = t & 63, wv = t >> 6;
  const int base = t * 32;
  const int4* rp = (const int4*)(route + base);
  unsigned mask = 0;
#pragma unroll
  for (int v = 0; v < 8; ++v) {
    int4 q = rp[v];
    mask |= (unsigned)(q.x == 0) << (v * 4 + 0);
    mask |= (unsigned)(q.y == 0) << (v * 4 + 1);
    mask |= (unsigned)(q.z == 0) << (v * 4 + 2);
    mask |= (unsigned)(q.w == 0) << (v * 4 + 3);
  }
  const int c0 = __popc(mask);
  int s = c0;                                   // within-wave inclusive scan
#pragma unroll
  for (int d = 1; d < 64; d <<= 1) {
    int v = __shfl_up(s, (unsigned)d, 64);
    if (lane >= d) s += v;
  }
  if (lane == 63) wsum[wv] = s;
  __syncthreads();
  int waveBase = 0, total0 = 0;
#pragma unroll
  for (int w = 0; w < 16; ++w) {
    int v = wsum[w];
    if (w < wv) waveBase += v;
    total0 += v;
  }
  const int ex0 = waveBase + s - c0;            // exclusive prefix of expert0 count
  int slot0 = ex0;
  int slot1 = NTOT - 1 - (base - ex0);
#pragma unroll
  for (int i = 0; i < 32; ++i) {
    int token = base + i;
    if ((mask >> i) & 1) idx[slot0++] = token;
    else                 idx[slot1--] = token;
  }
  if (t == 0) { counters[0] = total0; counters[1] = NT - total0; }
}

// ------- partition copy: xp[slot] = bf16(x[idx[slot]]), streaming, 16B/lane -------
// one-time convert, amortized 8x by the GEMM's column tiles (why split > fused).
__global__ __launch_bounds__(256) void copy_k(const float* __restrict__ x,
                                              const int* __restrict__ idx,
                                              const int* __restrict__ counters,
                                              unsigned short* __restrict__ xp) {
  const int t = threadIdx.x, lane = t & 63, wave = t >> 6;
  const int slot0 = blockIdx.x * 64;
  const int n0 = counters[0];
  for (int row = wave; row < 64; row += 4) {
    int slot = slot0 + row;
    if (slot >= n0 && slot < n0 + 128) continue;   // gap rows: left uninitialized,
    int tok = idx[slot];                           // gemm discards their outputs
    const float4* src = (const float4*)(x + (size_t)tok * DM);
    bf16x8* dst = (bf16x8*)(xp + (size_t)slot * DM);
#pragma unroll
    for (int p = 0; p < 2; ++p) {
      float4 v0 = src[p * 128 + lane * 2];
      float4 v1 = src[p * 128 + lane * 2 + 1];
      bf16x8 pk;                                   // native casts -> v_cvt_pk_bf16_f32
      pk[0] = (__bf16)v0.x; pk[1] = (__bf16)v0.y;
      pk[2] = (__bf16)v0.z; pk[3] = (__bf16)v0.w;
      pk[4] = (__bf16)v1.x; pk[5] = (__bf16)v1.y;
      pk[6] = (__bf16)v1.z; pk[7] = (__bf16)v1.w;
      dst[p * 64 + lane] = pk;
    }
  }
}

// ------- grouped GEMM: R0's proven structure + XCD swizzle (the ONE change) -------
// 128x128 tile, BK=64, 4 waves x (4x4) 16x16x32 MFMA, 32 KiB LDS, 4 blk/CU.
// LDS XOR-swizzle: global 16B-chunk c of row r lives at LDS chunk r*8 + (c^(r&7)).
__global__ __launch_bounds__(256, 4) void gemm_k(
    const unsigned short* __restrict__ xp,    // [NTOT][DM] bf16, partitioned
    const unsigned short* __restrict__ Wt,    // [2][DM][DM] bf16, Wt[n][k]
    const float* __restrict__ b1, const float* __restrict__ b2,
    const int* __restrict__ idx, const int* __restrict__ counters,
    float* __restrict__ out) {
  __shared__ unsigned short As[128 * 64];   // swizzled [row][k-chunk]
  __shared__ unsigned short Bs[128 * 64];

  const int t = threadIdx.x;
  const int lane = t & 63, wave = t >> 6;

  // XCD-aware bijective swizzle: 2056 blocks = 8 XCDs x 257. XCD k gets
  // consecutive logical ids walking col-fast -> A-panel (256 KB) reused by 8
  // consecutive blocks, Wt (4 MB) L2-resident per XCD.
  const int lin = blockIdx.y * 8 + blockIdx.x;       // dispatch order, x fastest
  const int L = (lin & 7) * 257 + (lin >> 3);        // bijective since 2056 % 8 == 0
  const int row0 = (L >> 3) * 128;
  const int col0 = (L & 7) * 128;

  const int n0 = counters[0];
  const int expert = (row0 < n0) ? 0 : 1;   // 128-gap => tiles never mix experts
  const unsigned short* Wte = Wt + (size_t)expert * DM * DM;
  const float* bias = expert ? b2 : b1;

  const int wr = (wave >> 1) * 64;
  const int wc = (wave & 1) * 64;
  const int lr = lane & 15;

  f32x4 acc[4][4] = {};

  for (int k0 = 0; k0 < DM; k0 += 64) {
#pragma unroll
    for (int p = 0; p < 4; ++p) {
      int q = p * 256 + t;          // 1024 chunks of 16B per 128x64 tile
      int r = q >> 3;
      int c = ((q & 7) ^ (r & 7)) * 8;   // swizzled global element offset
      GLD16(xp  + (size_t)(row0 + r) * DM + k0 + c, As + q * 8);
      GLD16(Wte + (size_t)(col0 + r) * DM + k0 + c, Bs + q * 8);
    }
    __syncthreads();
#pragma unroll
    for (int s = 0; s < 2; ++s) {
      const int cb = s * 4 + (lane >> 4);   // wanted 16B chunk within the row
      bf16x8 af[4], bfr[4];
#pragma unroll
      for (int i = 0; i < 4; ++i) {
        int r = wr + i * 16 + lr;
        af[i] = *(const bf16x8*)&As[(r * 8 + (cb ^ (r & 7))) * 8];
      }
#pragma unroll
      for (int j = 0; j < 4; ++j) {
        int r = wc + j * 16 + lr;
        bfr[j] = *(const bf16x8*)&Bs[(r * 8 + (cb ^ (r & 7))) * 8];
      }
#pragma unroll
      for (int i = 0; i < 4; ++i)
#pragma unroll
        for (int j = 0; j < 4; ++j)
          acc[i][j] = __builtin_amdgcn_mfma_f32_16x16x32_bf16(af[i], bfr[j], acc[i][j], 0, 0, 0);
    }
    __syncthreads();
  }

  // epilogue: scatter rows to original token positions, add bias (fp32).
  // gap rows [n0, n0+128) are discarded (their idx/xp were never written).
#pragma unroll
  for (int i = 0; i < 4; ++i) {
#pragma unroll
    for (int reg = 0; reg < 4; ++reg) {
      int gr = row0 + wr + i * 16 + (lane >> 4) * 4 + reg;
      if (gr < n0 || gr >= n0 + 128) {
        int dest = idx[gr];
#pragma unroll
        for (int j = 0; j < 4; ++j) {
          int gc = col0 + wc + j * 16 + (lane & 15);
          out[(size_t)dest * DM + gc] = acc[i][j][reg] + bias[gc];
        }
      }
    }
  }
}

extern "C" void kernel_launch(void* const* d_in, const int* in_sizes, int n_in,
                              void* d_out, int out_size, void* d_ws, size_t ws_size,
                              hipStream_t stream) {
  const float* x   = (const float*)d_in[0];
  const float* W1  = (const float*)d_in[1];
  const float* b1  = (const float*)d_in[2];
  const float* W2  = (const float*)d_in[3];
  const float* b2  = (const float*)d_in[4];
  const int*   route = (const int*)d_in[5];
  float* out = (float*)d_out;

  char* ws = (char*)d_ws;
  unsigned short* xp = (unsigned short*)ws;                       // NTOT*DM bf16
  size_t off = (size_t)NTOT * DM * 2;
  unsigned short* Wt = (unsigned short*)(ws + off);               // 2*DM*DM bf16
  off += (size_t)2 * DM * DM * 2;
  int* idx = (int*)(ws + off);                                    // NTOT ints
  int* counters = idx + NTOT;                                     // 2 ints

  route_k<<<1, 1024, 0, stream>>>(route, idx, counters);
  copy_k<<<NTOT / 64, 256, 0, stream>>>(x, idx, counters, xp);
  wt_k<<<dim3(DM / 32, DM / 32, 2), dim3(32, 8), 0, stream>>>(W1, W2, Wt);
  gemm_k<<<dim3(8, NTOT / 128), 256, 0, stream>>>(xp, Wt, b1, b2, idx, counters, out);
}